// Round 2
// baseline (1555.096 us; speedup 1.0000x reference)
//
#include <hip/hip_runtime.h>
#include <hip/hip_bf16.h>
#include <stdint.h>

// GCN: per layer  X_agg = (A_sym + D^-1) X ;  Y = X_agg @ W ; BN(gamma,beta) ; relu
// bias b cancels through BN -> skipped. agg-before-GEMM is exact-math equivalent.
// X stored panel-major: [K/16][MPAD][16 bf16 cols] (32 B/row/panel, panel = 3.2 MB -> fits 4MB XCD L2).
// Aggregation is column-sliced and XCD-pinned (slice = blockIdx.x & 7) for L2-resident gathers.

#define NN 100000
#define EE 1600000
#define BB 64
#define MPAD 100096   // 1564*64, zero-padded rows

typedef __attribute__((ext_vector_type(8))) short short8;
typedef __attribute__((ext_vector_type(4))) float f32x4;

__device__ __forceinline__ float bflo(uint32_t v){ return __uint_as_float(v << 16); }
__device__ __forceinline__ float bfhi(uint32_t v){ return __uint_as_float(v & 0xffff0000u); }
__device__ __forceinline__ uint32_t bfrne(float x){
  uint32_t u = __float_as_uint(x);
  return (u + 0x7fffu + ((u >> 16) & 1u)) >> 16;
}
__device__ __forceinline__ uint32_t bfpack(float a, float b){ return bfrne(a) | (bfrne(b) << 16); }

__device__ __forceinline__ void gload_lds16(const void* g, void* l){
  __builtin_amdgcn_global_load_lds(
      (const __attribute__((address_space(1))) uint32_t*)g,
      (__attribute__((address_space(3))) uint32_t*)l, 16, 0, 0);
}

// ---------------- setup: degree, rsqrt, CSR ----------------
__global__ void k_deg(const int* __restrict__ dst, int* __restrict__ degi){
  for (int e = blockIdx.x * blockDim.x + threadIdx.x; e < EE; e += gridDim.x * blockDim.x)
    atomicAdd(&degi[dst[e]], 1);
}

__global__ void k_dis(const int* __restrict__ degi, float* __restrict__ dis){
  int n = blockIdx.x * 256 + threadIdx.x;
  if (n < NN) dis[n] = rsqrtf((float)degi[n] + 1.0f);
}

__global__ void k_scan1(const int* __restrict__ degi, int* __restrict__ rp, int* __restrict__ bsum){
  __shared__ int lds[256];
  int b = blockIdx.x, t = threadIdx.x;
  int base = b * 1024 + t * 4;
  int v0 = (base + 0 < NN) ? degi[base + 0] : 0;
  int v1 = (base + 1 < NN) ? degi[base + 1] : 0;
  int v2 = (base + 2 < NN) ? degi[base + 2] : 0;
  int v3 = (base + 3 < NN) ? degi[base + 3] : 0;
  int s = v0 + v1 + v2 + v3;
  lds[t] = s; __syncthreads();
  for (int off = 1; off < 256; off <<= 1){
    int x = (t >= off) ? lds[t - off] : 0; __syncthreads();
    lds[t] += x; __syncthreads();
  }
  int excl = lds[t] - s;
  if (t == 255) bsum[b] = lds[255];
  if (base + 0 < NN) rp[base + 0] = excl;
  if (base + 1 < NN) rp[base + 1] = excl + v0;
  if (base + 2 < NN) rp[base + 2] = excl + v0 + v1;
  if (base + 3 < NN) rp[base + 3] = excl + v0 + v1 + v2;
}

__global__ void k_scan2(int* __restrict__ bsum, int nb){
  if (blockIdx.x == 0 && threadIdx.x == 0){
    int run = 0;
    for (int i = 0; i < nb; ++i){ int t = bsum[i]; bsum[i] = run; run += t; }
  }
}

__global__ void k_scan3(int* __restrict__ rp, int* __restrict__ cursor, const int* __restrict__ bsum){
  int b = blockIdx.x, t = threadIdx.x;
  int add = bsum[b];
  int base = b * 1024 + t * 4;
  #pragma unroll
  for (int j = 0; j < 4; ++j){
    int i = base + j;
    if (i < NN){ int v = rp[i] + add; rp[i] = v; cursor[i] = v; }
  }
  if (b == 0 && t == 0) rp[NN] = EE;
}

__global__ void k_fill(const int* __restrict__ src, const int* __restrict__ dst,
                       const float* __restrict__ dis, int* __restrict__ cursor,
                       long long* __restrict__ cp){
  for (int e = blockIdx.x * blockDim.x + threadIdx.x; e < EE; e += gridDim.x * blockDim.x){
    int s = src[e], d = dst[e];
    int pos = atomicAdd(&cursor[d], 1);
    float nrm = dis[s] * dis[d];
    long long v = (long long)(unsigned int)s | ((long long)(unsigned int)__float_as_uint(nrm) << 32);
    cp[pos] = v;
  }
}

// ---------------- weights -> bf16 panel-major: Wt[k/16][256][16] ----------------
__global__ void k_wt(const float* __restrict__ W, uint16_t* __restrict__ Wt, int K){
  int i = blockIdx.x * 256 + threadIdx.x;   // i = ((p16*256)+c)*16 + kk
  if (i >= 256 * K) return;
  int p16 = i >> 12, c = (i >> 4) & 255, kk = i & 15;
  Wt[i] = (uint16_t)bfrne(W[(p16 * 16 + kk) * 256 + c]);
}

// ---------------- x (f32 row-major [N][128]) -> bf16 panel-major [8][MPAD][16] ----------------
__global__ void k_cvtx(const float* __restrict__ x, uint4* __restrict__ X){
  int i = blockIdx.x * 256 + threadIdx.x;   // over MPAD*8
  if (i >= MPAD * 8) return;
  int row = i >> 3, c16 = i & 7;
  uint4 o0 = {0,0,0,0}, o1 = {0,0,0,0};
  if (row < NN){
    const float* xp = x + (size_t)row * 128 + c16 * 16;
    f32x4 v0 = *(const f32x4*)(xp);
    f32x4 v1 = *(const f32x4*)(xp + 4);
    f32x4 v2 = *(const f32x4*)(xp + 8);
    f32x4 v3 = *(const f32x4*)(xp + 12);
    o0.x = bfpack(v0[0], v0[1]); o0.y = bfpack(v0[2], v0[3]);
    o0.z = bfpack(v1[0], v1[1]); o0.w = bfpack(v1[2], v1[3]);
    o1.x = bfpack(v2[0], v2[1]); o1.y = bfpack(v2[2], v2[3]);
    o1.z = bfpack(v3[0], v3[1]); o1.w = bfpack(v3[2], v3[3]);
  }
  size_t o = ((size_t)c16 * MPAD + row) * 2;
  X[o] = o0; X[o + 1] = o1;
}

// ---------------- sliced aggregation (panel-major, XCD-pinned) ----------------
// slice = (blockIdx.x & 7) + 8*blockIdx.y ; 4 lanes x uint2 cover one 32B row-slice.
__global__ void k_aggs(const uint2* __restrict__ X2, const int* __restrict__ rp,
                       const long long* __restrict__ cp, const float* __restrict__ dis,
                       uint2* __restrict__ O2){
  int slice = (blockIdx.x & 7) + (blockIdx.y << 3);
  int rb = blockIdx.x >> 3;
  int j = threadIdx.x & 3;
  int row = rb * 64 + (threadIdx.x >> 2);
  const uint2* Xs = X2 + (size_t)slice * MPAD * 4;
  uint2* Os = O2 + (size_t)slice * MPAD * 4;
  if (row >= NN){
    __builtin_nontemporal_store(0ull, (unsigned long long*)&Os[(size_t)row * 4 + j]);
    return;
  }
  int beg = rp[row], end = rp[row + 1];
  float a0 = 0.f, a1 = 0.f, a2 = 0.f, a3 = 0.f;
  int e = beg;
  for (; e + 2 <= end; e += 2){
    long long p0 = __builtin_nontemporal_load(&cp[e]);
    long long p1 = __builtin_nontemporal_load(&cp[e + 1]);
    int s0 = (int)p0; float w0 = __uint_as_float((uint32_t)((unsigned long long)p0 >> 32));
    int s1 = (int)p1; float w1 = __uint_as_float((uint32_t)((unsigned long long)p1 >> 32));
    uint2 v0 = Xs[(size_t)s0 * 4 + j];
    uint2 v1 = Xs[(size_t)s1 * 4 + j];
    a0 += w0 * bflo(v0.x) + w1 * bflo(v1.x);
    a1 += w0 * bfhi(v0.x) + w1 * bfhi(v1.x);
    a2 += w0 * bflo(v0.y) + w1 * bflo(v1.y);
    a3 += w0 * bfhi(v0.y) + w1 * bfhi(v1.y);
  }
  if (e < end){
    long long p0 = __builtin_nontemporal_load(&cp[e]);
    int s0 = (int)p0; float w0 = __uint_as_float((uint32_t)((unsigned long long)p0 >> 32));
    uint2 v0 = Xs[(size_t)s0 * 4 + j];
    a0 += w0 * bflo(v0.x); a1 += w0 * bfhi(v0.x);
    a2 += w0 * bflo(v0.y); a3 += w0 * bfhi(v0.y);
  }
  float dv = dis[row]; float sn = dv * dv;
  uint2 vs = Xs[(size_t)row * 4 + j];
  a0 += sn * bflo(vs.x); a1 += sn * bfhi(vs.x);
  a2 += sn * bflo(vs.y); a3 += sn * bfhi(vs.y);
  unsigned long long rr = (unsigned long long)bfpack(a0, a1) | ((unsigned long long)bfpack(a2, a3) << 32);
  __builtin_nontemporal_store(rr, (unsigned long long*)&Os[(size_t)row * 4 + j]);
}

// ---------------- GEMM: Y[MPAD][256] = A * W, bf16 MFMA, fused BN column-stats ----------------
template<int K>
__global__ __launch_bounds__(256) void k_gemm(const uint16_t* __restrict__ A,
                                              const uint16_t* __restrict__ B,
                                              float* __restrict__ C,
                                              float* __restrict__ gstat){
  // LDS chunk layout: chunk c (16B) at lds + c*8 shorts; c = k8*128 + row
  __shared__ __align__(16) uint16_t lA[2][4096];
  __shared__ __align__(16) uint16_t lB[2][4096];
  __shared__ float lstat[256];
  int tid = threadIdx.x;
  int l = tid & 63;
  int bm = blockIdx.x, bn = blockIdx.y;
  lstat[tid] = 0.f;

  f32x4 acc[4][4];
  #pragma unroll
  for (int m = 0; m < 4; ++m)
    #pragma unroll
    for (int n = 0; n < 4; ++n){ f32x4 z = {0.f,0.f,0.f,0.f}; acc[m][n] = z; }

  int w = tid >> 6, wr = w >> 1, wc = w & 1;
  int rbase = wr * 64, cbase = wc * 64;
  int lrow = l & 15, lk8 = l >> 4;

  auto stage = [&](int kt, int buf){
    #pragma unroll
    for (int i = 0; i < 2; ++i){
      int c = i * 256 + tid;
      int k8 = c >> 7, r = c & 127;
      int kk = kt * 4 + k8;
      size_t ga = (size_t)((kk >> 1) * MPAD + bm * 128 + r) * 32 + (size_t)(kk & 1) * 16;
      size_t gb = (size_t)((kk >> 1) * 256  + bn * 128 + r) * 32 + (size_t)(kk & 1) * 16;
      gload_lds16((const char*)A + ga, (char*)&lA[buf][c * 8]);
      gload_lds16((const char*)B + gb, (char*)&lB[buf][c * 8]);
    }
  };

  stage(0, 0);
  __syncthreads();
  constexpr int NT = K / 32;
  for (int kt = 0; kt < NT; ++kt){
    int cur = kt & 1;
    if (kt + 1 < NT) stage(kt + 1, cur ^ 1);
    short8 afr[4], bfr[4];
    #pragma unroll
    for (int m = 0; m < 4; ++m)
      afr[m] = *(const short8*)&lA[cur][(lk8 * 128 + rbase + m * 16 + lrow) * 8];
    #pragma unroll
    for (int n = 0; n < 4; ++n)
      bfr[n] = *(const short8*)&lB[cur][(lk8 * 128 + cbase + n * 16 + lrow) * 8];
    #pragma unroll
    for (int m = 0; m < 4; ++m)
      #pragma unroll
      for (int n = 0; n < 4; ++n)
        acc[m][n] = __builtin_amdgcn_mfma_f32_16x16x32_bf16(afr[m], bfr[n], acc[m][n], 0, 0, 0);
    __syncthreads();
  }

  // C write (C/D layout: col = lane&15, row = (lane>>4)*4 + reg)
  int grow0 = bm * 128 + rbase + (l >> 4) * 4;
  int gcol0 = bn * 128 + cbase + (l & 15);
  float sa[4] = {0.f,0.f,0.f,0.f}, sb[4] = {0.f,0.f,0.f,0.f};
  #pragma unroll
  for (int m = 0; m < 4; ++m){
    #pragma unroll
    for (int n = 0; n < 4; ++n){
      int col = gcol0 + n * 16;
      int r0 = grow0 + m * 16;
      f32x4 v = acc[m][n];
      #pragma unroll
      for (int q = 0; q < 4; ++q){
        C[(size_t)(r0 + q) * 256 + col] = v[q];
        sa[n] += v[q]; sb[n] += v[q] * v[q];
      }
    }
  }
  #pragma unroll
  for (int n = 0; n < 4; ++n){
    int cl = wc * 64 + n * 16 + lrow;
    atomicAdd(&lstat[cl], sa[n]);
    atomicAdd(&lstat[128 + cl], sb[n]);
  }
  __syncthreads();
  if (tid < 128){
    atomicAdd(&gstat[bn * 128 + tid], lstat[tid]);
    atomicAdd(&gstat[256 + bn * 128 + tid], lstat[128 + tid]);
  }
}

__global__ void k_finalize(const float* __restrict__ stats, const float* __restrict__ gamma,
                           const float* __restrict__ beta, float* __restrict__ ss){
  int c = threadIdx.x;
  float mean = stats[c] / (float)NN;
  float var  = stats[256 + c] / (float)NN - mean * mean;
  float rstd = rsqrtf(var + 1e-5f);
  float sc = gamma[c] * rstd;
  ss[c] = sc;
  ss[256 + c] = beta[c] - mean * sc;
}

// ---------------- BN + relu + cast -> panel-major bf16 [16][MPAD][16] ----------------
__global__ void k_bnapply(const float* __restrict__ Y, const float* __restrict__ ss,
                          uint4* __restrict__ X){
  int i = blockIdx.x * 256 + threadIdx.x;    // over MPAD*16
  if (i >= MPAD * 16) return;
  int row = i >> 4, c16 = i & 15;
  const float* y = Y + (size_t)row * 256 + c16 * 16;
  int c0 = c16 * 16;
  float r[16];
  #pragma unroll
  for (int jj = 0; jj < 16; jj += 4){
    f32x4 v = *(const f32x4*)(y + jj);
    #pragma unroll
    for (int q = 0; q < 4; ++q)
      r[jj + q] = fmaxf(v[q] * ss[c0 + jj + q] + ss[256 + c0 + jj + q], 0.f);
  }
  uint4 o0, o1;
  o0.x = bfpack(r[0], r[1]);  o0.y = bfpack(r[2], r[3]);
  o0.z = bfpack(r[4], r[5]);  o0.w = bfpack(r[6], r[7]);
  o1.x = bfpack(r[8], r[9]);  o1.y = bfpack(r[10], r[11]);
  o1.z = bfpack(r[12], r[13]); o1.w = bfpack(r[14], r[15]);
  size_t o = ((size_t)c16 * MPAD + row) * 2;
  X[o] = o0; X[o + 1] = o1;
}

// ---------------- segment starts + pooling (panel-major input) ----------------
__global__ void k_segstart(const int* __restrict__ batch, int* __restrict__ seg){
  int g = threadIdx.x;
  if (g > BB) return;
  if (g == BB){ seg[BB] = NN; return; }
  int lo = 0, hi = NN;
  while (lo < hi){ int mid = (lo + hi) >> 1; if (batch[mid] < g) lo = mid + 1; else hi = mid; }
  seg[g] = lo;
}

__global__ void k_pool(const uint32_t* __restrict__ X, const int* __restrict__ seg,
                       float* __restrict__ out){
  int g = blockIdx.x, t = threadIdx.x;    // 128 threads, 2 adjacent cols each
  int s = seg[g], e = seg[g + 1];
  int panel = t >> 3, u = t & 7;
  const uint32_t* base = X + ((size_t)panel * MPAD) * 8 + u;
  float sm0 = 0.f, sm1 = 0.f, mx0 = 0.f, mx1 = 0.f;
  #pragma unroll 4
  for (int r = s; r < e; ++r){
    uint32_t v = base[(size_t)r * 8];
    float a = bflo(v), b2 = bfhi(v);
    sm0 += a; sm1 += b2;
    mx0 = fmaxf(mx0, a); mx1 = fmaxf(mx1, b2);
  }
  float inv = 1.0f / (float)(e - s);
  int c = panel * 16 + u * 2;
  out[g * 512 + c] = sm0 * inv;
  out[g * 512 + c + 1] = sm1 * inv;
  out[g * 512 + 256 + c] = mx0;
  out[g * 512 + 256 + c + 1] = mx1;
}

// ---------------- launch ----------------
extern "C" void kernel_launch(void* const* d_in, const int* in_sizes, int n_in,
                              void* d_out, int out_size, void* d_ws, size_t ws_size,
                              hipStream_t stream){
  const float* x     = (const float*)d_in[0];
  const float* W0    = (const float*)d_in[1];
  const float* Wr    = (const float*)d_in[2];
  const float* gamma = (const float*)d_in[4];
  const float* beta  = (const float*)d_in[5];
  const int*   ei    = (const int*)d_in[6];
  const int*   batch = (const int*)d_in[7];
  const int* esrc = ei;
  const int* edst = ei + EE;
  float* out = (float*)d_out;

  char* base = (char*)d_ws;
  size_t off = 0;
  auto alloc = [&](size_t b)->char*{
    char* p = base + off; off = (off + b + 255) & ~(size_t)255; return p;
  };
  uint32_t* Xbuf = (uint32_t*)alloc((size_t)MPAD * 256 * 2);  // bf16 panel-major
  uint32_t* Xagg = (uint32_t*)alloc((size_t)MPAD * 256 * 2);
  float*    Y    = (float*)   alloc((size_t)MPAD * 256 * 4);
  uint16_t* Wt0  = (uint16_t*)alloc(256 * 128 * 2);
  uint16_t* Wt1  = (uint16_t*)alloc(256 * 256 * 2);
  uint16_t* Wt2  = (uint16_t*)alloc(256 * 256 * 2);
  int*   degi   = (int*)  alloc((size_t)NN * 4);
  float* dis    = (float*)alloc((size_t)NN * 4);
  int*   rp     = (int*)  alloc((size_t)(NN + 1) * 4);
  int*   cursor = (int*)  alloc((size_t)NN * 4);
  int*   bsum   = (int*)  alloc(128 * 4);
  long long* cp = (long long*)alloc((size_t)EE * 8);
  float* stats  = (float*)alloc(512 * 4);
  float* ss     = (float*)alloc(512 * 4);
  int*   seg    = (int*)  alloc((BB + 1) * 4);

  hipMemsetAsync(degi, 0, (size_t)NN * 4, stream);
  k_deg<<<2048, 256, 0, stream>>>(edst, degi);
  k_dis<<<391, 256, 0, stream>>>(degi, dis);
  k_scan1<<<98, 256, 0, stream>>>(degi, rp, bsum);
  k_scan2<<<1, 1, 0, stream>>>(bsum, 98);
  k_scan3<<<98, 256, 0, stream>>>(rp, cursor, bsum);
  k_fill<<<2048, 256, 0, stream>>>(esrc, edst, dis, cursor, cp);
  k_wt<<<128, 256, 0, stream>>>(W0, Wt0, 128);
  k_wt<<<256, 256, 0, stream>>>(Wr, Wt1, 256);
  k_wt<<<256, 256, 0, stream>>>(Wr + 256 * 256, Wt2, 256);
  k_cvtx<<<(MPAD * 8 + 255) / 256, 256, 0, stream>>>(x, (uint4*)Xbuf);

  const uint2* Xb2 = (const uint2*)Xbuf;
  const uint2* Xa2c = (const uint2*)Xagg;
  uint2* Xa2 = (uint2*)Xagg;
  uint2* Xb2w = (uint2*)Xbuf;

  // layer 1 (K=128)
  hipMemsetAsync(stats, 0, 512 * 4, stream);
  k_aggs<<<dim3(8 * (MPAD / 64), 1), 256, 0, stream>>>(Xb2, rp, cp, dis, Xa2);
  k_gemm<128><<<dim3(MPAD / 128, 2), 256, 0, stream>>>((const uint16_t*)Xagg, Wt0, Y, stats);
  k_finalize<<<1, 256, 0, stream>>>(stats, gamma + 0, beta + 0, ss);
  k_bnapply<<<(MPAD * 16 + 255) / 256, 256, 0, stream>>>(Y, ss, (uint4*)Xbuf);

  // layer 2 (K=256)
  hipMemsetAsync(stats, 0, 512 * 4, stream);
  k_aggs<<<dim3(8 * (MPAD / 64), 2), 256, 0, stream>>>(Xb2, rp, cp, dis, Xa2);
  k_gemm<256><<<dim3(MPAD / 128, 2), 256, 0, stream>>>((const uint16_t*)Xagg, Wt1, Y, stats);
  k_finalize<<<1, 256, 0, stream>>>(stats, gamma + 256, beta + 256, ss);
  k_bnapply<<<(MPAD * 16 + 255) / 256, 256, 0, stream>>>(Y, ss, (uint4*)Xbuf);

  // layer 3 (K=256)
  hipMemsetAsync(stats, 0, 512 * 4, stream);
  k_aggs<<<dim3(8 * (MPAD / 64), 2), 256, 0, stream>>>(Xb2, rp, cp, dis, Xa2);
  k_gemm<256><<<dim3(MPAD / 128, 2), 256, 0, stream>>>((const uint16_t*)Xagg, Wt2, Y, stats);
  k_finalize<<<1, 256, 0, stream>>>(stats, gamma + 512, beta + 512, ss);
  k_bnapply<<<(MPAD * 16 + 255) / 256, 256, 0, stream>>>(Y, ss, (uint4*)Xbuf);

  // pooling
  k_segstart<<<1, 128, 0, stream>>>(batch, seg);
  k_pool<<<BB, 128, 0, stream>>>(Xbuf, seg, out);
}

// Round 3
// 919.338 us; speedup vs baseline: 1.6915x; 1.6915x over previous
//
#include <hip/hip_runtime.h>
#include <hip/hip_bf16.h>
#include <stdint.h>

// GCN: per layer  X_agg = (A_sym + D^-1) X ;  Y = X_agg @ W ; BN(gamma,beta) ; relu
// bias b cancels through BN -> skipped. agg-before-GEMM is exact-math equivalent.
// X row-major bf16 [MPAD][K]; gather = 512B contiguous per edge (K=256).
// Y stored bf16; BN stats fused into GEMM epilogue (f32 accs, 8-replica atomics).

#define NN 100000
#define EE 1600000
#define BB 64
#define MPAD 100096   // 782*128, zero-padded rows

typedef __attribute__((ext_vector_type(8))) short short8;
typedef __attribute__((ext_vector_type(4))) float f32x4;

__device__ __forceinline__ float bflo(uint32_t v){ return __uint_as_float(v << 16); }
__device__ __forceinline__ float bfhi(uint32_t v){ return __uint_as_float(v & 0xffff0000u); }
__device__ __forceinline__ uint32_t bfrne(float x){
  uint32_t u = __float_as_uint(x);
  return (u + 0x7fffu + ((u >> 16) & 1u)) >> 16;
}
__device__ __forceinline__ uint32_t bfpack(float a, float b){ return bfrne(a) | (bfrne(b) << 16); }

__device__ __forceinline__ void gload_lds16(const void* g, void* l){
  __builtin_amdgcn_global_load_lds(
      (const __attribute__((address_space(1))) uint32_t*)g,
      (__attribute__((address_space(3))) uint32_t*)l, 16, 0, 0);
}

// ---------------- setup: degree, rsqrt, CSR ----------------
__global__ void k_deg(const int* __restrict__ dst, int* __restrict__ degi){
  for (int e = blockIdx.x * blockDim.x + threadIdx.x; e < EE; e += gridDim.x * blockDim.x)
    atomicAdd(&degi[dst[e]], 1);
}

__global__ void k_dis(const int* __restrict__ degi, float* __restrict__ dis){
  int n = blockIdx.x * 256 + threadIdx.x;
  if (n < NN) dis[n] = rsqrtf((float)degi[n] + 1.0f);
}

__global__ void k_scan1(const int* __restrict__ degi, int* __restrict__ rp, int* __restrict__ bsum){
  __shared__ int lds[256];
  int b = blockIdx.x, t = threadIdx.x;
  int base = b * 1024 + t * 4;
  int v0 = (base + 0 < NN) ? degi[base + 0] : 0;
  int v1 = (base + 1 < NN) ? degi[base + 1] : 0;
  int v2 = (base + 2 < NN) ? degi[base + 2] : 0;
  int v3 = (base + 3 < NN) ? degi[base + 3] : 0;
  int s = v0 + v1 + v2 + v3;
  lds[t] = s; __syncthreads();
  for (int off = 1; off < 256; off <<= 1){
    int x = (t >= off) ? lds[t - off] : 0; __syncthreads();
    lds[t] += x; __syncthreads();
  }
  int excl = lds[t] - s;
  if (t == 255) bsum[b] = lds[255];
  if (base + 0 < NN) rp[base + 0] = excl;
  if (base + 1 < NN) rp[base + 1] = excl + v0;
  if (base + 2 < NN) rp[base + 2] = excl + v0 + v1;
  if (base + 3 < NN) rp[base + 3] = excl + v0 + v1 + v2;
}

__global__ void k_scan2(int* __restrict__ bsum, int nb){
  if (blockIdx.x == 0 && threadIdx.x == 0){
    int run = 0;
    for (int i = 0; i < nb; ++i){ int t = bsum[i]; bsum[i] = run; run += t; }
  }
}

__global__ void k_scan3(int* __restrict__ rp, int* __restrict__ cursor, const int* __restrict__ bsum){
  int b = blockIdx.x, t = threadIdx.x;
  int add = bsum[b];
  int base = b * 1024 + t * 4;
  #pragma unroll
  for (int j = 0; j < 4; ++j){
    int i = base + j;
    if (i < NN){ int v = rp[i] + add; rp[i] = v; cursor[i] = v; }
  }
  if (b == 0 && t == 0) rp[NN] = EE;
}

__global__ void k_fill(const int* __restrict__ src, const int* __restrict__ dst,
                       const float* __restrict__ dis, int* __restrict__ cursor,
                       long long* __restrict__ cp){
  for (int e = blockIdx.x * blockDim.x + threadIdx.x; e < EE; e += gridDim.x * blockDim.x){
    int s = src[e], d = dst[e];
    int pos = atomicAdd(&cursor[d], 1);
    float nrm = dis[s] * dis[d];
    long long v = (long long)(unsigned int)s | ((long long)(unsigned int)__float_as_uint(nrm) << 32);
    cp[pos] = v;
  }
}

// ---------------- weight transpose to bf16:  Wt[c][k] = W[k][c] ----------------
__global__ void k_wt(const float* __restrict__ W, uint16_t* __restrict__ Wt, int K){
  int i = blockIdx.x * 256 + threadIdx.x;   // i = c*K + k
  if (i >= 256 * K) return;
  int c = i / K, k = i - c * K;
  Wt[i] = (uint16_t)bfrne(W[k * 256 + c]);
}

// ---------------- x (f32) -> bf16 row-major [MPAD][128], zero-pad rows ----------------
__global__ void k_cvtx(const float* __restrict__ x, uint32_t* __restrict__ Xb){
  int i = blockIdx.x * 256 + threadIdx.x;   // over MPAD*64
  if (i >= MPAD * 64) return;
  int row = i >> 6;
  uint32_t r = 0u;
  if (row < NN){
    int col = (i & 63) * 2;
    r = bfpack(x[row * 128 + col], x[row * 128 + col + 1]);
  }
  Xb[i] = r;
}

// ---------------- aggregation: Xout[row] = sum_e nrm*Xin[src] + (1/deg)*Xin[row] ----------------
template<int K>
__global__ void k_agg(const uint32_t* __restrict__ Xin, const int* __restrict__ rp,
                      const long long* __restrict__ cp, const float* __restrict__ dis,
                      uint32_t* __restrict__ Xout){
  constexpr int LPR = K / 2;          // uint lanes per row
  constexpr int RPAR = 256 / LPR;     // rows in parallel
  constexpr int SEQ = 4;
  int lane = threadIdx.x & (LPR - 1);
  int slot = threadIdx.x / LPR;
  int row0 = blockIdx.x * (RPAR * SEQ);
  for (int rr = 0; rr < SEQ; ++rr){
    int row = row0 + rr * RPAR + slot;
    if (row >= MPAD) continue;
    if (row >= NN){ Xout[(size_t)row * LPR + lane] = 0u; continue; }
    int beg = rp[row], end = rp[row + 1];
    float a0 = 0.f, a1 = 0.f;
    int e = beg;
    for (; e + 8 <= end; e += 8){
      long long p[8];
      #pragma unroll
      for (int u = 0; u < 8; ++u) p[u] = cp[e + u];
      uint32_t v[8];
      #pragma unroll
      for (int u = 0; u < 8; ++u) v[u] = Xin[(size_t)(int)p[u] * LPR + lane];
      #pragma unroll
      for (int u = 0; u < 8; ++u){
        float w = __uint_as_float((uint32_t)((unsigned long long)p[u] >> 32));
        a0 += w * bflo(v[u]); a1 += w * bfhi(v[u]);
      }
    }
    for (; e < end; ++e){
      long long p0 = cp[e];
      int s = (int)p0; float w = __uint_as_float((uint32_t)((unsigned long long)p0 >> 32));
      uint32_t v = Xin[(size_t)s * LPR + lane];
      a0 += w * bflo(v); a1 += w * bfhi(v);
    }
    float dv = dis[row]; float sn = dv * dv;
    uint32_t vs = Xin[(size_t)row * LPR + lane];
    a0 += sn * bflo(vs); a1 += sn * bfhi(vs);
    Xout[(size_t)row * LPR + lane] = bfpack(a0, a1);
  }
}

// ---------------- GEMM: Y[MPAD][256](bf16) = A[MPAD][K] * Wt[256][K]^T, fused BN stats ----------------
template<int K>
__global__ __launch_bounds__(256) void k_gemm(const uint16_t* __restrict__ A,
                                              const uint16_t* __restrict__ Bt,
                                              uint32_t* __restrict__ Cb,
                                              float* __restrict__ gstat){
  // LDS chunk layout: chunk c (16B) at lds + c*8 shorts; c = k8*128 + row
  __shared__ __align__(16) uint16_t lA[2][4096];
  __shared__ __align__(16) uint16_t lB[2][4096];
  __shared__ float lstat[256];
  int tid = threadIdx.x;
  int l = tid & 63;
  int bm = blockIdx.x, bn = blockIdx.y;
  lstat[tid] = 0.f;

  f32x4 acc[4][4];
  #pragma unroll
  for (int m = 0; m < 4; ++m)
    #pragma unroll
    for (int n = 0; n < 4; ++n){ f32x4 z = {0.f,0.f,0.f,0.f}; acc[m][n] = z; }

  int w = tid >> 6, wr = w >> 1, wc = w & 1;
  int rbase = wr * 64, cbase = wc * 64;
  int lrow = l & 15, lk8 = l >> 4;

  auto stage = [&](int kt, int buf){
    #pragma unroll
    for (int i = 0; i < 2; ++i){
      int c = i * 256 + tid;
      int k8 = c >> 7, r = c & 127;
      size_t ga = (size_t)(bm * 128 + r) * K + kt * 32 + k8 * 8;
      size_t gb = (size_t)(bn * 128 + r) * K + kt * 32 + k8 * 8;
      gload_lds16((const char*)(A + ga), (char*)&lA[buf][c * 8]);
      gload_lds16((const char*)(Bt + gb), (char*)&lB[buf][c * 8]);
    }
  };

  stage(0, 0);
  __syncthreads();
  constexpr int NT = K / 32;
  for (int kt = 0; kt < NT; ++kt){
    int cur = kt & 1;
    if (kt + 1 < NT) stage(kt + 1, cur ^ 1);
    short8 afr[4], bfr[4];
    #pragma unroll
    for (int m = 0; m < 4; ++m)
      afr[m] = *(const short8*)&lA[cur][(lk8 * 128 + rbase + m * 16 + lrow) * 8];
    #pragma unroll
    for (int n = 0; n < 4; ++n)
      bfr[n] = *(const short8*)&lB[cur][(lk8 * 128 + cbase + n * 16 + lrow) * 8];
    #pragma unroll
    for (int m = 0; m < 4; ++m)
      #pragma unroll
      for (int n = 0; n < 4; ++n)
        acc[m][n] = __builtin_amdgcn_mfma_f32_16x16x32_bf16(afr[m], bfr[n], acc[m][n], 0, 0, 0);
    __syncthreads();
  }

  // C write bf16 (C/D layout: col = lane&15, row = (lane>>4)*4 + reg) + column stats
  int grow0 = bm * 128 + rbase + (l >> 4) * 4;
  int gcol0 = bn * 128 + cbase + (l & 15);
  uint16_t* C16 = (uint16_t*)Cb;
  float sa[4] = {0.f,0.f,0.f,0.f}, sb[4] = {0.f,0.f,0.f,0.f};
  #pragma unroll
  for (int m = 0; m < 4; ++m){
    #pragma unroll
    for (int n = 0; n < 4; ++n){
      int col = gcol0 + n * 16;
      int r0 = grow0 + m * 16;
      f32x4 v = acc[m][n];
      #pragma unroll
      for (int q = 0; q < 4; ++q){
        C16[(size_t)(r0 + q) * 256 + col] = (uint16_t)bfrne(v[q]);
        sa[n] += v[q]; sb[n] += v[q] * v[q];
      }
    }
  }
  #pragma unroll
  for (int n = 0; n < 4; ++n){
    int cl = wc * 64 + n * 16 + lrow;
    atomicAdd(&lstat[cl], sa[n]);
    atomicAdd(&lstat[128 + cl], sb[n]);
  }
  __syncthreads();
  // 8-replica global accumulation (cap same-address atomic depth)
  float* rep = gstat + (size_t)(bm & 7) * 512;
  if (tid < 128){
    atomicAdd(&rep[bn * 128 + tid], lstat[tid]);
    atomicAdd(&rep[256 + bn * 128 + tid], lstat[128 + tid]);
  }
}

__global__ void k_finalize(const float* __restrict__ stats, const float* __restrict__ gamma,
                           const float* __restrict__ beta, float* __restrict__ ss){
  int c = threadIdx.x;
  float s = 0.f, s2 = 0.f;
  #pragma unroll
  for (int r = 0; r < 8; ++r){
    s  += stats[r * 512 + c];
    s2 += stats[r * 512 + 256 + c];
  }
  float mean = s / (float)NN;
  float var  = s2 / (float)NN - mean * mean;
  float rstd = rsqrtf(var + 1e-5f);
  float sc = gamma[c] * rstd;
  ss[c] = sc;
  ss[256 + c] = beta[c] - mean * sc;
}

// ---------------- BN + relu on bf16 Y -> bf16 X row-major [MPAD][256] ----------------
__global__ void k_bnapply(const uint4* __restrict__ Y, const float* __restrict__ ss,
                          uint4* __restrict__ X){
  int i = blockIdx.x * 256 + threadIdx.x;    // over MPAD*32, 8 bf16 each
  if (i >= MPAD * 32) return;
  uint4 v = Y[i];
  int c0 = (i & 31) * 8;
  float r0 = fmaxf(bflo(v.x) * ss[c0 + 0] + ss[256 + c0 + 0], 0.f);
  float r1 = fmaxf(bfhi(v.x) * ss[c0 + 1] + ss[256 + c0 + 1], 0.f);
  float r2 = fmaxf(bflo(v.y) * ss[c0 + 2] + ss[256 + c0 + 2], 0.f);
  float r3 = fmaxf(bfhi(v.y) * ss[c0 + 3] + ss[256 + c0 + 3], 0.f);
  float r4 = fmaxf(bflo(v.z) * ss[c0 + 4] + ss[256 + c0 + 4], 0.f);
  float r5 = fmaxf(bfhi(v.z) * ss[c0 + 5] + ss[256 + c0 + 5], 0.f);
  float r6 = fmaxf(bflo(v.w) * ss[c0 + 6] + ss[256 + c0 + 6], 0.f);
  float r7 = fmaxf(bfhi(v.w) * ss[c0 + 7] + ss[256 + c0 + 7], 0.f);
  uint4 o;
  o.x = bfpack(r0, r1); o.y = bfpack(r2, r3);
  o.z = bfpack(r4, r5); o.w = bfpack(r6, r7);
  X[i] = o;
}

// ---------------- segment starts + pooling ----------------
__global__ void k_segstart(const int* __restrict__ batch, int* __restrict__ seg){
  int g = threadIdx.x;
  if (g > BB) return;
  if (g == BB){ seg[BB] = NN; return; }
  int lo = 0, hi = NN;
  while (lo < hi){ int mid = (lo + hi) >> 1; if (batch[mid] < g) lo = mid + 1; else hi = mid; }
  seg[g] = lo;
}

__global__ void k_pool(const uint32_t* __restrict__ X, const int* __restrict__ seg,
                       float* __restrict__ out){
  int g = blockIdx.x, t = threadIdx.x;    // 128 threads, 2 adjacent cols each
  int s = seg[g], e = seg[g + 1];
  float sm0 = 0.f, sm1 = 0.f, mx0 = 0.f, mx1 = 0.f;
  #pragma unroll 4
  for (int r = s; r < e; ++r){
    uint32_t v = X[(size_t)r * 128 + t];
    float a = bflo(v), b2 = bfhi(v);
    sm0 += a; sm1 += b2;
    mx0 = fmaxf(mx0, a); mx1 = fmaxf(mx1, b2);
  }
  float inv = 1.0f / (float)(e - s);
  out[g * 512 + 2 * t] = sm0 * inv;
  out[g * 512 + 2 * t + 1] = sm1 * inv;
  out[g * 512 + 256 + 2 * t] = mx0;
  out[g * 512 + 256 + 2 * t + 1] = mx1;
}

// ---------------- launch ----------------
extern "C" void kernel_launch(void* const* d_in, const int* in_sizes, int n_in,
                              void* d_out, int out_size, void* d_ws, size_t ws_size,
                              hipStream_t stream){
  const float* x     = (const float*)d_in[0];
  const float* W0    = (const float*)d_in[1];
  const float* Wr    = (const float*)d_in[2];
  const float* gamma = (const float*)d_in[4];
  const float* beta  = (const float*)d_in[5];
  const int*   ei    = (const int*)d_in[6];
  const int*   batch = (const int*)d_in[7];
  const int* esrc = ei;
  const int* edst = ei + EE;
  float* out = (float*)d_out;

  char* base = (char*)d_ws;
  size_t off = 0;
  auto alloc = [&](size_t b)->char*{
    char* p = base + off; off = (off + b + 255) & ~(size_t)255; return p;
  };
  uint32_t* Xbuf = (uint32_t*)alloc((size_t)MPAD * 256 * 2);  // bf16 row-major
  uint32_t* Xagg = (uint32_t*)alloc((size_t)MPAD * 256 * 2);
  uint32_t* Y    = (uint32_t*)alloc((size_t)MPAD * 256 * 2);  // bf16 pre-BN
  uint16_t* Wt0  = (uint16_t*)alloc(256 * 128 * 2);
  uint16_t* Wt1  = (uint16_t*)alloc(256 * 256 * 2);
  uint16_t* Wt2  = (uint16_t*)alloc(256 * 256 * 2);
  int*   degi   = (int*)  alloc((size_t)NN * 4);
  float* dis    = (float*)alloc((size_t)NN * 4);
  int*   rp     = (int*)  alloc((size_t)(NN + 1) * 4);
  int*   cursor = (int*)  alloc((size_t)NN * 4);
  int*   bsum   = (int*)  alloc(128 * 4);
  long long* cp = (long long*)alloc((size_t)EE * 8);
  float* stats  = (float*)alloc(8 * 512 * 4);
  float* ss     = (float*)alloc(512 * 4);
  int*   seg    = (int*)  alloc((BB + 1) * 4);

  hipMemsetAsync(degi, 0, (size_t)NN * 4, stream);
  k_deg<<<2048, 256, 0, stream>>>(edst, degi);
  k_dis<<<391, 256, 0, stream>>>(degi, dis);
  k_scan1<<<98, 256, 0, stream>>>(degi, rp, bsum);
  k_scan2<<<1, 1, 0, stream>>>(bsum, 98);
  k_scan3<<<98, 256, 0, stream>>>(rp, cursor, bsum);
  k_fill<<<2048, 256, 0, stream>>>(esrc, edst, dis, cursor, cp);
  k_wt<<<128, 256, 0, stream>>>(W0, Wt0, 128);
  k_wt<<<256, 256, 0, stream>>>(Wr, Wt1, 256);
  k_wt<<<256, 256, 0, stream>>>(Wr + 256 * 256, Wt2, 256);
  k_cvtx<<<MPAD * 64 / 256, 256, 0, stream>>>(x, Xbuf);

  // layer 1 (K=128)
  hipMemsetAsync(stats, 0, 8 * 512 * 4, stream);
  k_agg<128><<<MPAD / 16, 256, 0, stream>>>(Xbuf, rp, cp, dis, Xagg);
  k_gemm<128><<<dim3(MPAD / 128, 2), 256, 0, stream>>>((const uint16_t*)Xagg, Wt0, Y, stats);
  k_finalize<<<1, 256, 0, stream>>>(stats, gamma + 0, beta + 0, ss);
  k_bnapply<<<MPAD * 32 / 256, 256, 0, stream>>>((const uint4*)Y, ss, (uint4*)Xbuf);

  // layer 2 (K=256)
  hipMemsetAsync(stats, 0, 8 * 512 * 4, stream);
  k_agg<256><<<MPAD / 8, 256, 0, stream>>>(Xbuf, rp, cp, dis, Xagg);
  k_gemm<256><<<dim3(MPAD / 128, 2), 256, 0, stream>>>((const uint16_t*)Xagg, Wt1, Y, stats);
  k_finalize<<<1, 256, 0, stream>>>(stats, gamma + 256, beta + 256, ss);
  k_bnapply<<<MPAD * 32 / 256, 256, 0, stream>>>((const uint4*)Y, ss, (uint4*)Xbuf);

  // layer 3 (K=256)
  hipMemsetAsync(stats, 0, 8 * 512 * 4, stream);
  k_agg<256><<<MPAD / 8, 256, 0, stream>>>(Xbuf, rp, cp, dis, Xagg);
  k_gemm<256><<<dim3(MPAD / 128, 2), 256, 0, stream>>>((const uint16_t*)Xagg, Wt2, Y, stats);
  k_finalize<<<1, 256, 0, stream>>>(stats, gamma + 512, beta + 512, ss);
  k_bnapply<<<MPAD * 32 / 256, 256, 0, stream>>>((const uint4*)Y, ss, (uint4*)Xbuf);

  // pooling
  k_segstart<<<1, 128, 0, stream>>>(batch, seg);
  k_pool<<<BB, 128, 0, stream>>>(Xbuf, seg, out);
}

// Round 4
// 770.213 us; speedup vs baseline: 2.0190x; 1.1936x over previous
//
#include <hip/hip_runtime.h>
#include <hip/hip_bf16.h>
#include <stdint.h>

// GCN: per layer  X_agg = (A_sym + D^-1) X ;  Y = X_agg @ W ; BN(gamma,beta) ; relu
// bias b cancels through BN -> skipped. agg-before-GEMM is exact-math equivalent.
// X row-major bf16 [MPAD][K]; gather = one 512B wave-transaction per edge (uint2/lane).
// Y bf16; BN stats fused into GEMM epilogue (f32 accs, 8-replica atomics).

#define NN 100000
#define EE 1600000
#define BB 64
#define MPAD 100096   // 391*256, zero-padded rows

typedef __attribute__((ext_vector_type(8))) short short8;
typedef __attribute__((ext_vector_type(4))) float f32x4;

__device__ __forceinline__ float bflo(uint32_t v){ return __uint_as_float(v << 16); }
__device__ __forceinline__ float bfhi(uint32_t v){ return __uint_as_float(v & 0xffff0000u); }
__device__ __forceinline__ uint32_t bfrne(float x){
  uint32_t u = __float_as_uint(x);
  return (u + 0x7fffu + ((u >> 16) & 1u)) >> 16;
}
__device__ __forceinline__ uint32_t bfpack(float a, float b){ return bfrne(a) | (bfrne(b) << 16); }
__device__ __forceinline__ float phi(long long p){
  return __uint_as_float((uint32_t)((unsigned long long)p >> 32));
}

__device__ __forceinline__ void gload_lds16(const void* g, void* l){
  __builtin_amdgcn_global_load_lds(
      (const __attribute__((address_space(1))) uint32_t*)g,
      (__attribute__((address_space(3))) uint32_t*)l, 16, 0, 0);
}

// ---------------- setup: degree, rsqrt, CSR ----------------
__global__ void k_deg(const int* __restrict__ dst, int* __restrict__ degi){
  for (int e = blockIdx.x * blockDim.x + threadIdx.x; e < EE; e += gridDim.x * blockDim.x)
    atomicAdd(&degi[dst[e]], 1);
}

__global__ void k_scan1(const int* __restrict__ degi, int* __restrict__ rp, int* __restrict__ bsum,
                        float* __restrict__ dis){
  __shared__ int lds[256];
  int b = blockIdx.x, t = threadIdx.x;
  int base = b * 1024 + t * 4;
  int v0 = (base + 0 < NN) ? degi[base + 0] : 0;
  int v1 = (base + 1 < NN) ? degi[base + 1] : 0;
  int v2 = (base + 2 < NN) ? degi[base + 2] : 0;
  int v3 = (base + 3 < NN) ? degi[base + 3] : 0;
  if (base + 0 < NN) dis[base + 0] = rsqrtf((float)v0 + 1.0f);
  if (base + 1 < NN) dis[base + 1] = rsqrtf((float)v1 + 1.0f);
  if (base + 2 < NN) dis[base + 2] = rsqrtf((float)v2 + 1.0f);
  if (base + 3 < NN) dis[base + 3] = rsqrtf((float)v3 + 1.0f);
  int s = v0 + v1 + v2 + v3;
  lds[t] = s; __syncthreads();
  for (int off = 1; off < 256; off <<= 1){
    int x = (t >= off) ? lds[t - off] : 0; __syncthreads();
    lds[t] += x; __syncthreads();
  }
  int excl = lds[t] - s;
  if (t == 255) bsum[b] = lds[255];
  if (base + 0 < NN) rp[base + 0] = excl;
  if (base + 1 < NN) rp[base + 1] = excl + v0;
  if (base + 2 < NN) rp[base + 2] = excl + v0 + v1;
  if (base + 3 < NN) rp[base + 3] = excl + v0 + v1 + v2;
}

__global__ void k_scan2(int* __restrict__ bsum, int nb){
  if (blockIdx.x == 0 && threadIdx.x == 0){
    int run = 0;
    for (int i = 0; i < nb; ++i){ int t = bsum[i]; bsum[i] = run; run += t; }
  }
}

__global__ void k_scan3(int* __restrict__ rp, int* __restrict__ cursor, const int* __restrict__ bsum){
  int b = blockIdx.x, t = threadIdx.x;
  int add = bsum[b];
  int base = b * 1024 + t * 4;
  #pragma unroll
  for (int j = 0; j < 4; ++j){
    int i = base + j;
    if (i < NN){ int v = rp[i] + add; rp[i] = v; cursor[i] = v; }
  }
  if (b == 0 && t == 0) rp[NN] = EE;
}

__global__ void k_fill(const int* __restrict__ src, const int* __restrict__ dst,
                       const float* __restrict__ dis, int* __restrict__ cursor,
                       long long* __restrict__ cp){
  for (int e = blockIdx.x * blockDim.x + threadIdx.x; e < EE; e += gridDim.x * blockDim.x){
    int s = src[e], d = dst[e];
    int pos = atomicAdd(&cursor[d], 1);
    float nrm = dis[s] * dis[d];
    long long v = (long long)(unsigned int)s | ((long long)(unsigned int)__float_as_uint(nrm) << 32);
    cp[pos] = v;
  }
}

// ---------------- all weights -> bf16 transposed Wt[c][k] ----------------
__global__ void k_wtall(const float* __restrict__ W0, const float* __restrict__ Wr,
                        uint16_t* __restrict__ Wt0, uint16_t* __restrict__ Wt1,
                        uint16_t* __restrict__ Wt2){
  int i = blockIdx.x * 256 + threadIdx.x;   // 32768 + 65536 + 65536
  if (i < 32768){
    int c = i >> 7, k = i & 127;
    Wt0[i] = (uint16_t)bfrne(W0[k * 256 + c]);
  } else if (i < 32768 + 131072){
    int j = i - 32768;
    int m = j >> 16, jj = j & 65535;
    int c = jj >> 8, k = jj & 255;
    uint16_t v = (uint16_t)bfrne(Wr[m * 65536 + k * 256 + c]);
    if (m == 0) Wt1[jj] = v; else Wt2[jj] = v;
  }
}

// ---------------- x (f32) -> bf16 row-major [MPAD][128], zero-pad rows ----------------
__global__ void k_cvtx(const float* __restrict__ x, uint32_t* __restrict__ Xb){
  int i = blockIdx.x * 256 + threadIdx.x;   // over MPAD*64
  if (i >= MPAD * 64) return;
  int row = i >> 6;
  uint32_t r = 0u;
  if (row < NN){
    int col = (i & 63) * 2;
    r = bfpack(x[row * 128 + col], x[row * 128 + col + 1]);
  }
  Xb[i] = r;
}

// ---------------- aggregation K=256: one wave per row, uint2 per lane ----------------
__global__ void k_agg256(const uint2* __restrict__ Xin, const int* __restrict__ rp,
                         const long long* __restrict__ cp, const float* __restrict__ dis,
                         uint2* __restrict__ Xout){
  int lane = threadIdx.x & 63;
  int slot = threadIdx.x >> 6;
  int row0 = blockIdx.x * 16 + slot;
  for (int rr = 0; rr < 4; ++rr){
    int row = row0 + rr * 4;
    if (row >= NN){
      if (row < MPAD){ uint2 z = {0u, 0u}; Xout[(size_t)row * 64 + lane] = z; }
      continue;
    }
    int beg = rp[row], end = rp[row + 1];
    float a0 = 0.f, a1 = 0.f, a2 = 0.f, a3 = 0.f;
    int e = beg;
    for (; e + 8 <= end; e += 8){
      long long p[8]; uint2 v[8];
      #pragma unroll
      for (int u = 0; u < 8; ++u) p[u] = cp[e + u];
      #pragma unroll
      for (int u = 0; u < 8; ++u) v[u] = Xin[(size_t)(int)p[u] * 64 + lane];
      #pragma unroll
      for (int u = 0; u < 8; ++u){
        float w = phi(p[u]);
        a0 += w * bflo(v[u].x); a1 += w * bfhi(v[u].x);
        a2 += w * bflo(v[u].y); a3 += w * bfhi(v[u].y);
      }
    }
    for (; e < end; ++e){
      long long p0 = cp[e];
      float w = phi(p0);
      uint2 v = Xin[(size_t)(int)p0 * 64 + lane];
      a0 += w * bflo(v.x); a1 += w * bfhi(v.x);
      a2 += w * bflo(v.y); a3 += w * bfhi(v.y);
    }
    float dv = dis[row]; float sn = dv * dv;
    uint2 vs = Xin[(size_t)row * 64 + lane];
    a0 += sn * bflo(vs.x); a1 += sn * bfhi(vs.x);
    a2 += sn * bflo(vs.y); a3 += sn * bfhi(vs.y);
    uint2 o; o.x = bfpack(a0, a1); o.y = bfpack(a2, a3);
    Xout[(size_t)row * 64 + lane] = o;
  }
}

// ---------------- aggregation K=128: half-wave pair, uint2 per lane ----------------
__global__ void k_agg128(const uint2* __restrict__ Xin, const int* __restrict__ rp,
                         const long long* __restrict__ cp, const float* __restrict__ dis,
                         uint2* __restrict__ Xout){
  int lane = threadIdx.x & 63;
  int half = lane >> 5, j = lane & 31;
  int slot = threadIdx.x >> 6;
  int row0 = blockIdx.x * 16 + slot;
  for (int rr = 0; rr < 4; ++rr){
    int row = row0 + rr * 4;
    if (row >= NN){
      if (row < MPAD && half == 0){ uint2 z = {0u, 0u}; Xout[(size_t)row * 32 + j] = z; }
      continue;
    }
    int beg = rp[row], end = rp[row + 1];
    float a0 = 0.f, a1 = 0.f, a2 = 0.f, a3 = 0.f;
    int e = beg;
    for (; e + 8 <= end; e += 8){
      long long p[4]; uint2 v[4];
      #pragma unroll
      for (int u = 0; u < 4; ++u) p[u] = cp[e + u * 2 + half];
      #pragma unroll
      for (int u = 0; u < 4; ++u) v[u] = Xin[(size_t)(int)p[u] * 32 + j];
      #pragma unroll
      for (int u = 0; u < 4; ++u){
        float w = phi(p[u]);
        a0 += w * bflo(v[u].x); a1 += w * bfhi(v[u].x);
        a2 += w * bflo(v[u].y); a3 += w * bfhi(v[u].y);
      }
    }
    for (; e < end; e += 2){
      int idx = e + half;
      bool ok = idx < end;
      long long p0 = cp[ok ? idx : end - 1];
      float w = ok ? phi(p0) : 0.f;
      uint2 v = Xin[(size_t)(int)p0 * 32 + j];
      a0 += w * bflo(v.x); a1 += w * bfhi(v.x);
      a2 += w * bflo(v.y); a3 += w * bfhi(v.y);
    }
    a0 += __shfl_xor(a0, 32); a1 += __shfl_xor(a1, 32);
    a2 += __shfl_xor(a2, 32); a3 += __shfl_xor(a3, 32);
    if (half == 0){
      float dv = dis[row]; float sn = dv * dv;
      uint2 vs = Xin[(size_t)row * 32 + j];
      a0 += sn * bflo(vs.x); a1 += sn * bfhi(vs.x);
      a2 += sn * bflo(vs.y); a3 += sn * bfhi(vs.y);
      uint2 o; o.x = bfpack(a0, a1); o.y = bfpack(a2, a3);
      Xout[(size_t)row * 32 + j] = o;
    }
  }
}

// ---------------- GEMM: Y[MPAD][256](bf16) = A[MPAD][K] * Wt[256][K]^T, fused BN stats ----------------
// 256x128 tile, 512 threads (8 waves, 4x2), double-buffered global_load_lds staging.
template<int K>
__global__ __launch_bounds__(512) void k_gemm(const uint16_t* __restrict__ A,
                                              const uint16_t* __restrict__ Bt,
                                              uint32_t* __restrict__ Cb,
                                              float* __restrict__ gstat){
  __shared__ __align__(16) uint16_t lA[2][8192];   // chunk c = k8*256 + r
  __shared__ __align__(16) uint16_t lB[2][4096];   // chunk c = k8*128 + r
  __shared__ float lstat[256];
  int tid = threadIdx.x;
  int l = tid & 63;
  int bm = blockIdx.x, bn = blockIdx.y;
  if (tid < 256) lstat[tid] = 0.f;

  f32x4 acc[4][4];
  #pragma unroll
  for (int m = 0; m < 4; ++m)
    #pragma unroll
    for (int n = 0; n < 4; ++n){ f32x4 z = {0.f,0.f,0.f,0.f}; acc[m][n] = z; }

  int w = tid >> 6, wr = w >> 1, wc = w & 1;
  int rbase = wr * 64, cbase = wc * 64;
  int lrow = l & 15, lk8 = l >> 4;

  auto stage = [&](int kt, int buf){
    #pragma unroll
    for (int i = 0; i < 2; ++i){
      int c = i * 512 + tid;
      int k8 = c >> 8, r = c & 255;
      size_t ga = (size_t)(bm * 256 + r) * K + kt * 32 + k8 * 8;
      gload_lds16((const char*)(A + ga), (char*)&lA[buf][c * 8]);
    }
    int k8b = tid >> 7, rb = tid & 127;
    size_t gb = (size_t)(bn * 128 + rb) * K + kt * 32 + k8b * 8;
    gload_lds16((const char*)(Bt + gb), (char*)&lB[buf][tid * 8]);
  };

  stage(0, 0);
  __syncthreads();
  constexpr int NT = K / 32;
  for (int kt = 0; kt < NT; ++kt){
    int cur = kt & 1;
    if (kt + 1 < NT) stage(kt + 1, cur ^ 1);
    short8 afr[4], bfr[4];
    #pragma unroll
    for (int m = 0; m < 4; ++m)
      afr[m] = *(const short8*)&lA[cur][(lk8 * 256 + rbase + m * 16 + lrow) * 8];
    #pragma unroll
    for (int n = 0; n < 4; ++n)
      bfr[n] = *(const short8*)&lB[cur][(lk8 * 128 + cbase + n * 16 + lrow) * 8];
    #pragma unroll
    for (int m = 0; m < 4; ++m)
      #pragma unroll
      for (int n = 0; n < 4; ++n)
        acc[m][n] = __builtin_amdgcn_mfma_f32_16x16x32_bf16(afr[m], bfr[n], acc[m][n], 0, 0, 0);
    __syncthreads();
  }

  // C write bf16 (C/D: col = lane&15, row = (lane>>4)*4 + reg) + column stats
  int grow0 = bm * 256 + rbase + (l >> 4) * 4;
  int gcol0 = bn * 128 + cbase + (l & 15);
  uint16_t* C16 = (uint16_t*)Cb;
  float sa[4] = {0.f,0.f,0.f,0.f}, sb[4] = {0.f,0.f,0.f,0.f};
  #pragma unroll
  for (int m = 0; m < 4; ++m){
    #pragma unroll
    for (int n = 0; n < 4; ++n){
      int col = gcol0 + n * 16;
      int r0 = grow0 + m * 16;
      f32x4 v = acc[m][n];
      #pragma unroll
      for (int q = 0; q < 4; ++q){
        C16[(size_t)(r0 + q) * 256 + col] = (uint16_t)bfrne(v[q]);
        sa[n] += v[q]; sb[n] += v[q] * v[q];
      }
    }
  }
  #pragma unroll
  for (int n = 0; n < 4; ++n){
    int cl = cbase + n * 16 + lrow;
    atomicAdd(&lstat[cl], sa[n]);
    atomicAdd(&lstat[128 + cl], sb[n]);
  }
  __syncthreads();
  float* rep = gstat + (size_t)(bm & 7) * 512;
  if (tid < 128){
    atomicAdd(&rep[bn * 128 + tid], lstat[tid]);
    atomicAdd(&rep[256 + bn * 128 + tid], lstat[128 + tid]);
  }
}

// finalize: reduce 8 replicas -> scale/shift, then RE-ZERO stats for next layer.
__global__ void k_finalize(float* __restrict__ stats, const float* __restrict__ gamma,
                           const float* __restrict__ beta, float* __restrict__ ss){
  int c = threadIdx.x;
  float s = 0.f, s2 = 0.f;
  #pragma unroll
  for (int r = 0; r < 8; ++r){
    s  += stats[r * 512 + c];
    s2 += stats[r * 512 + 256 + c];
    stats[r * 512 + c] = 0.f;
    stats[r * 512 + 256 + c] = 0.f;
  }
  float mean = s / (float)NN;
  float var  = s2 / (float)NN - mean * mean;
  float rstd = rsqrtf(var + 1e-5f);
  float sc = gamma[c] * rstd;
  ss[c] = sc;
  ss[256 + c] = beta[c] - mean * sc;
}

// ---------------- BN + relu on bf16 Y -> bf16 X row-major [MPAD][256] ----------------
__global__ void k_bnapply(const uint4* __restrict__ Y, const float* __restrict__ ss,
                          uint4* __restrict__ X){
  int i = blockIdx.x * 256 + threadIdx.x;    // over MPAD*32, 8 bf16 each
  if (i >= MPAD * 32) return;
  uint4 v = Y[i];
  int c0 = (i & 31) * 8;
  float r0 = fmaxf(bflo(v.x) * ss[c0 + 0] + ss[256 + c0 + 0], 0.f);
  float r1 = fmaxf(bfhi(v.x) * ss[c0 + 1] + ss[256 + c0 + 1], 0.f);
  float r2 = fmaxf(bflo(v.y) * ss[c0 + 2] + ss[256 + c0 + 2], 0.f);
  float r3 = fmaxf(bfhi(v.y) * ss[c0 + 3] + ss[256 + c0 + 3], 0.f);
  float r4 = fmaxf(bflo(v.z) * ss[c0 + 4] + ss[256 + c0 + 4], 0.f);
  float r5 = fmaxf(bfhi(v.z) * ss[c0 + 5] + ss[256 + c0 + 5], 0.f);
  float r6 = fmaxf(bflo(v.w) * ss[c0 + 6] + ss[256 + c0 + 6], 0.f);
  float r7 = fmaxf(bfhi(v.w) * ss[c0 + 7] + ss[256 + c0 + 7], 0.f);
  uint4 o;
  o.x = bfpack(r0, r1); o.y = bfpack(r2, r3);
  o.z = bfpack(r4, r5); o.w = bfpack(r6, r7);
  X[i] = o;
}

// ---------------- segment starts + pooling (8-way row split) ----------------
__global__ void k_segstart(const int* __restrict__ batch, int* __restrict__ seg){
  int g = threadIdx.x;
  if (g > BB) return;
  if (g == BB){ seg[BB] = NN; return; }
  int lo = 0, hi = NN;
  while (lo < hi){ int mid = (lo + hi) >> 1; if (batch[mid] < g) lo = mid + 1; else hi = mid; }
  seg[g] = lo;
}

__global__ void k_poolpart(const uint32_t* __restrict__ X, const int* __restrict__ seg,
                           float* __restrict__ pb){
  int g = blockIdx.x, c = blockIdx.y, t = threadIdx.x;   // 128 threads
  int s = seg[g], e = seg[g + 1];
  int len = e - s;
  int c0 = s + (int)(((long long)len * c) >> 3);
  int c1 = s + (int)(((long long)len * (c + 1)) >> 3);
  float sm0 = 0.f, sm1 = 0.f, mx0 = -1e30f, mx1 = -1e30f;
  #pragma unroll 4
  for (int r = c0; r < c1; ++r){
    uint32_t v = X[(size_t)r * 128 + t];
    float a = bflo(v), b2 = bfhi(v);
    sm0 += a; sm1 += b2;
    mx0 = fmaxf(mx0, a); mx1 = fmaxf(mx1, b2);
  }
  float* p = pb + (size_t)(g * 8 + c) * 512;
  p[2 * t] = sm0; p[2 * t + 1] = sm1;
  p[256 + 2 * t] = mx0; p[256 + 2 * t + 1] = mx1;
}

__global__ void k_poolred(const float* __restrict__ pb, const int* __restrict__ seg,
                          float* __restrict__ out){
  int g = blockIdx.x, cc = threadIdx.x;   // 256 threads
  float s = 0.f, m = -1e30f;
  #pragma unroll
  for (int c = 0; c < 8; ++c){
    const float* p = pb + (size_t)(g * 8 + c) * 512;
    s += p[cc];
    m = fmaxf(m, p[256 + cc]);
  }
  float inv = 1.0f / (float)(seg[g + 1] - seg[g]);
  out[g * 512 + cc] = s * inv;
  out[g * 512 + 256 + cc] = m;
}

// ---------------- launch ----------------
extern "C" void kernel_launch(void* const* d_in, const int* in_sizes, int n_in,
                              void* d_out, int out_size, void* d_ws, size_t ws_size,
                              hipStream_t stream){
  const float* x     = (const float*)d_in[0];
  const float* W0    = (const float*)d_in[1];
  const float* Wr    = (const float*)d_in[2];
  const float* gamma = (const float*)d_in[4];
  const float* beta  = (const float*)d_in[5];
  const int*   ei    = (const int*)d_in[6];
  const int*   batch = (const int*)d_in[7];
  const int* esrc = ei;
  const int* edst = ei + EE;
  float* out = (float*)d_out;

  char* base = (char*)d_ws;
  size_t off = 0;
  auto alloc = [&](size_t b)->char*{
    char* p = base + off; off = (off + b + 255) & ~(size_t)255; return p;
  };
  uint32_t* Xbuf = (uint32_t*)alloc((size_t)MPAD * 256 * 2);  // bf16 row-major
  uint32_t* Xagg = (uint32_t*)alloc((size_t)MPAD * 256 * 2);
  uint32_t* Y    = (uint32_t*)alloc((size_t)MPAD * 256 * 2);  // bf16 pre-BN
  uint16_t* Wt0  = (uint16_t*)alloc(256 * 128 * 2);
  uint16_t* Wt1  = (uint16_t*)alloc(256 * 256 * 2);
  uint16_t* Wt2  = (uint16_t*)alloc(256 * 256 * 2);
  int*   degi   = (int*)  alloc((size_t)NN * 4);
  float* dis    = (float*)alloc((size_t)NN * 4);
  int*   rp     = (int*)  alloc((size_t)(NN + 1) * 4);
  int*   cursor = (int*)  alloc((size_t)NN * 4);
  int*   bsum   = (int*)  alloc(128 * 4);
  long long* cp = (long long*)alloc((size_t)EE * 8);
  float* stats  = (float*)alloc(8 * 512 * 4);
  float* ss     = (float*)alloc(512 * 4);
  int*   seg    = (int*)  alloc((BB + 1) * 4);
  float* pb     = (float*)alloc((size_t)BB * 8 * 512 * 4);

  hipMemsetAsync(degi, 0, (size_t)NN * 4, stream);
  hipMemsetAsync(stats, 0, 8 * 512 * 4, stream);
  k_deg<<<2048, 256, 0, stream>>>(edst, degi);
  k_scan1<<<98, 256, 0, stream>>>(degi, rp, bsum, dis);
  k_scan2<<<1, 1, 0, stream>>>(bsum, 98);
  k_scan3<<<98, 256, 0, stream>>>(rp, cursor, bsum);
  k_fill<<<2048, 256, 0, stream>>>(esrc, edst, dis, cursor, cp);
  k_wtall<<<640, 256, 0, stream>>>(W0, Wr, Wt0, Wt1, Wt2);
  k_cvtx<<<MPAD * 64 / 256, 256, 0, stream>>>(x, Xbuf);

  // layer 1 (K=128)
  k_agg128<<<MPAD / 16, 256, 0, stream>>>((const uint2*)Xbuf, rp, cp, dis, (uint2*)Xagg);
  k_gemm<128><<<dim3(MPAD / 256, 2), 512, 0, stream>>>((const uint16_t*)Xagg, Wt0, Y, stats);
  k_finalize<<<1, 256, 0, stream>>>(stats, gamma + 0, beta + 0, ss);
  k_bnapply<<<MPAD * 32 / 256, 256, 0, stream>>>((const uint4*)Y, ss, (uint4*)Xbuf);

  // layer 2 (K=256)
  k_agg256<<<MPAD / 16, 256, 0, stream>>>((const uint2*)Xbuf, rp, cp, dis, (uint2*)Xagg);
  k_gemm<256><<<dim3(MPAD / 256, 2), 512, 0, stream>>>((const uint16_t*)Xagg, Wt1, Y, stats);
  k_finalize<<<1, 256, 0, stream>>>(stats, gamma + 256, beta + 256, ss);
  k_bnapply<<<MPAD * 32 / 256, 256, 0, stream>>>((const uint4*)Y, ss, (uint4*)Xbuf);

  // layer 3 (K=256)
  k_agg256<<<MPAD / 16, 256, 0, stream>>>((const uint2*)Xbuf, rp, cp, dis, (uint2*)Xagg);
  k_gemm<256><<<dim3(MPAD / 256, 2), 512, 0, stream>>>((const uint16_t*)Xagg, Wt2, Y, stats);
  k_finalize<<<1, 256, 0, stream>>>(stats, gamma + 512, beta + 512, ss);
  k_bnapply<<<MPAD * 32 / 256, 256, 0, stream>>>((const uint4*)Y, ss, (uint4*)Xbuf);

  // pooling
  k_segstart<<<1, 128, 0, stream>>>(batch, seg);
  k_poolpart<<<dim3(BB, 8), 128, 0, stream>>>(Xbuf, seg, pb);
  k_poolred<<<BB, 256, 0, stream>>>(pb, seg, out);
}